// Round 1
// baseline (3430.627 us; speedup 1.0000x reference)
//
#include <hip/hip_runtime.h>
#include <hip/hip_bf16.h>
#include <math.h>

#define S_TOK 8192
#define DMODEL 2048
#define HIDDEN_ 8192
#define NEXP 8
#define CAPACITY 2048

typedef __bf16 bf16x8 __attribute__((ext_vector_type(8)));
typedef float f32x4 __attribute__((ext_vector_type(4)));

__device__ __forceinline__ unsigned short f2bf(float f) {
  union { float fv; unsigned u; } v; v.fv = f;
  unsigned r = v.u + 0x7fffu + ((v.u >> 16) & 1u);
  return (unsigned short)(r >> 16);
}

__device__ __forceinline__ void llds16(const void* g, void* l) {
  __builtin_amdgcn_global_load_lds(
      (const __attribute__((address_space(1))) unsigned*)g,
      (__attribute__((address_space(3))) unsigned*)l, 16, 0, 0);
}

// ---------------- gate: fp64 logits, top-2, normalized gates ----------------
__global__ __launch_bounds__(256) void gate_kernel(const float* __restrict__ x,
                                                   const float* __restrict__ wg,
                                                   int* __restrict__ eidx,
                                                   float* __restrict__ egate) {
  const int lane = threadIdx.x & 63;
  const int wave = threadIdx.x >> 6;
  const int t = blockIdx.x * 4 + wave;
  const float* xt = x + (size_t)t * DMODEL;
  double acc[NEXP];
#pragma unroll
  for (int e = 0; e < NEXP; ++e) acc[e] = 0.0;
  for (int i = lane; i < DMODEL; i += 64) {
    double xv = (double)xt[i];
    const float4* wr = (const float4*)(wg + (size_t)i * NEXP);
    float4 w0 = wr[0], w1 = wr[1];
    acc[0] += xv * (double)w0.x; acc[1] += xv * (double)w0.y;
    acc[2] += xv * (double)w0.z; acc[3] += xv * (double)w0.w;
    acc[4] += xv * (double)w1.x; acc[5] += xv * (double)w1.y;
    acc[6] += xv * (double)w1.z; acc[7] += xv * (double)w1.w;
  }
#pragma unroll
  for (int m = 32; m > 0; m >>= 1) {
#pragma unroll
    for (int e = 0; e < NEXP; ++e) acc[e] += __shfl_xor(acc[e], m, 64);
  }
  if (lane == 0) {
    int e1 = 0; double v1 = acc[0];
#pragma unroll
    for (int e = 1; e < NEXP; ++e) if (acc[e] > v1) { v1 = acc[e]; e1 = e; }
    int e2 = -1; double v2 = 0.0;
#pragma unroll
    for (int e = 0; e < NEXP; ++e) {
      if (e == e1) continue;
      if (e2 < 0 || acc[e] > v2) { v2 = acc[e]; e2 = e; }
    }
    double d = exp(v2 - v1);           // <= 1
    double g1 = 1.0 / (1.0 + d);       // p1/(p1+p2), softmax denom cancels
    eidx[t * 2] = e1; eidx[t * 2 + 1] = e2;
    egate[t * 2] = (float)g1;
    egate[t * 2 + 1] = (float)(d / (1.0 + d));
  }
}

// ------- scan: tutel two-pass cumsum -> slot_src / slot_gate (1 block) ------
__global__ __launch_bounds__(256) void scan_kernel(const int* __restrict__ eidx,
                                                   const float* __restrict__ egate,
                                                   int* __restrict__ slot_src,
                                                   float* __restrict__ slot_gate) {
  __shared__ int cnt[NEXP][257];
  __shared__ int totals[NEXP];
  const int t = threadIdx.x;
  int base[NEXP];
#pragma unroll
  for (int e = 0; e < NEXP; ++e) base[e] = 0;
  for (int s = 0; s < 2; ++s) {
    int local[NEXP];
#pragma unroll
    for (int e = 0; e < NEXP; ++e) local[e] = 0;
    const int t0 = t * 32;
    for (int i = 0; i < 32; ++i) local[eidx[(t0 + i) * 2 + s]]++;
#pragma unroll
    for (int e = 0; e < NEXP; ++e) cnt[e][t] = local[e];
    __syncthreads();
    if (t < NEXP) {   // serial exclusive scan per expert (256 steps, cheap)
      int run = 0;
      for (int i = 0; i < 256; ++i) { int v = cnt[t][i]; cnt[t][i] = run; run += v; }
      totals[t] = run;
    }
    __syncthreads();
    int pos[NEXP];
#pragma unroll
    for (int e = 0; e < NEXP; ++e) pos[e] = cnt[e][t] + base[e];
    for (int i = 0; i < 32; ++i) {
      const int tok = t0 + i;
      const int e = eidx[tok * 2 + s];
      const int p = pos[e]++;
      if (p < CAPACITY) {
        slot_src[e * CAPACITY + p] = tok;
        slot_gate[e * CAPACITY + p] = egate[tok * 2 + s];
      }
    }
#pragma unroll
    for (int e = 0; e < NEXP; ++e) base[e] += totals[e];
    __syncthreads();
  }
}

// ------------- dispatch: gather token rows -> bf16 disp[E*C][D] -------------
__global__ __launch_bounds__(256) void dispatch_kernel(const float* __restrict__ x,
                                                       const int* __restrict__ slot_src,
                                                       unsigned short* __restrict__ disp) {
  const int slot = blockIdx.x;
  const int t = slot_src[slot];
  unsigned short* dst = disp + (size_t)slot * DMODEL + threadIdx.x * 8;
  if (t < 0) {
    uint4 z = {0u, 0u, 0u, 0u};
    *(uint4*)dst = z;
  } else {
    const float* src = x + (size_t)t * DMODEL + threadIdx.x * 8;
    float4 a = *(const float4*)src;
    float4 b = *(const float4*)(src + 4);
    uint4 o;
    o.x = f2bf(a.x) | ((unsigned)f2bf(a.y) << 16);
    o.y = f2bf(a.z) | ((unsigned)f2bf(a.w) << 16);
    o.z = f2bf(b.x) | ((unsigned)f2bf(b.y) << 16);
    o.w = f2bf(b.z) | ((unsigned)f2bf(b.w) << 16);
    *(uint4*)dst = o;
  }
}

// ---------- transpose+convert: W fp32 [K][N] -> WT bf16 [N][K] ----------
__global__ __launch_bounds__(256) void transpose_kernel(const float* __restrict__ W,
                                                        unsigned short* __restrict__ WT,
                                                        const int K, const int N) {
  __shared__ unsigned short ldsT[64][66];  // pad 66: write stride 132B -> 2-way (free)
  const int n0 = blockIdx.x * 64;
  const int k0 = blockIdx.y * 64;
  const int t = threadIdx.x;
#pragma unroll
  for (int i = 0; i < 4; ++i) {
    int lin = i * 256 + t;
    int kr = lin >> 4;
    int c4 = (lin & 15) * 4;
    float4 v = *(const float4*)(W + (size_t)(k0 + kr) * N + n0 + c4);
    ldsT[c4 + 0][kr] = f2bf(v.x);
    ldsT[c4 + 1][kr] = f2bf(v.y);
    ldsT[c4 + 2][kr] = f2bf(v.z);
    ldsT[c4 + 3][kr] = f2bf(v.w);
  }
  __syncthreads();
#pragma unroll
  for (int i = 0; i < 2; ++i) {
    int lin = i * 256 + t;
    int n = lin >> 3;
    int kc = (lin & 7) * 8;
    const unsigned* p = (const unsigned*)(const void*)&ldsT[n][kc];  // 4B-aligned
    uint4 o; o.x = p[0]; o.y = p[1]; o.z = p[2]; o.w = p[3];
    *(uint4*)(WT + (size_t)(n0 + n) * K + k0 + kc) = o;
  }
}

// ---------------- m97-style bf16 GEMM, 128x128 tile, BK=32 ----------------
// A [M][K] bf16 row-major, BT [N][K] bf16 row-major (both K-contiguous).
// EPI=0: Hout = bf16(gelu(acc + bias))   (grid.z == 1)
// EPI=1: y[slot_src[row]] += slot_gate[row] * (acc + bias@z0)  (split-K grid.z)
template <int EPI>
__global__ __launch_bounds__(256) void gemm_kernel(
    const unsigned short* __restrict__ A, const unsigned short* __restrict__ BT,
    const int M, const int N, const int K, const int kChunk,
    const float* __restrict__ bias, unsigned short* __restrict__ Hout,
    float* __restrict__ Yout, const int* __restrict__ slot_src,
    const float* __restrict__ slot_gate) {
  __shared__ unsigned short smA[128 * 32];
  __shared__ unsigned short smB[128 * 32];
  const int tid = threadIdx.x;
  const int lane = tid & 63;
  const int wave = tid >> 6;
  const int n0 = blockIdx.x * 128;
  const int m0 = blockIdx.y * 128;
  const int kbeg = blockIdx.z * kChunk;
  const int wm = wave >> 1;
  const int wn = wave & 1;

  // staging: 512 16B chunks, LDS dest = wave-uniform base + lane*16
  const int q1 = wave * 128 + lane;
  const int q2 = q1 + 64;
  const int rA1 = q1 >> 2, cA1 = (q1 & 3) * 8;
  const int rA2 = q2 >> 2, cA2 = (q2 & 3) * 8;
  const unsigned short* gA1 = A + (size_t)(m0 + rA1) * K + kbeg + cA1;
  const unsigned short* gA2 = A + (size_t)(m0 + rA2) * K + kbeg + cA2;
  const unsigned short* gB1 = BT + (size_t)(n0 + rA1) * K + kbeg + cA1;
  const unsigned short* gB2 = BT + (size_t)(n0 + rA2) * K + kbeg + cA2;
  unsigned short* lA1 = smA + q1 * 8;
  unsigned short* lA2 = smA + q2 * 8;
  unsigned short* lB1 = smB + q1 * 8;
  unsigned short* lB2 = smB + q2 * 8;

  f32x4 acc[4][4];
  const f32x4 vzero = {0.0f, 0.0f, 0.0f, 0.0f};
#pragma unroll
  for (int i = 0; i < 4; ++i)
#pragma unroll
    for (int j = 0; j < 4; ++j) acc[i][j] = vzero;

  const int kq = (lane >> 4) * 8;
  const int rm = lane & 15;

  const int iters = kChunk / 32;
  for (int kt = 0; kt < iters; ++kt) {
    __syncthreads();                 // prior compute done before overwrite
    llds16(gA1, lA1); llds16(gA2, lA2);
    llds16(gB1, lB1); llds16(gB2, lB2);
    gA1 += 32; gA2 += 32; gB1 += 32; gB2 += 32;
    __syncthreads();                 // compiler drains vmcnt before s_barrier
    bf16x8 af[4], bfr[4];
#pragma unroll
    for (int mi = 0; mi < 4; ++mi)
      af[mi] = *(const bf16x8*)(const void*)(smA + ((wm * 64 + mi * 16 + rm) * 32 + kq));
#pragma unroll
    for (int ni = 0; ni < 4; ++ni)
      bfr[ni] = *(const bf16x8*)(const void*)(smB + ((wn * 64 + ni * 16 + rm) * 32 + kq));
#pragma unroll
    for (int mi = 0; mi < 4; ++mi)
#pragma unroll
      for (int ni = 0; ni < 4; ++ni)
        acc[mi][ni] = __builtin_amdgcn_mfma_f32_16x16x32_bf16(af[mi], bfr[ni], acc[mi][ni], 0, 0, 0);
  }

  const int colb = n0 + wn * 64;
  const int rowb = m0 + wm * 64 + ((lane >> 4) << 2);
  if (EPI == 0) {
#pragma unroll
    for (int ni = 0; ni < 4; ++ni) {
      const int col = colb + ni * 16 + rm;
      const float bv = bias[col];
#pragma unroll
      for (int mi = 0; mi < 4; ++mi) {
        const int row = rowb + mi * 16;
        f32x4 v = acc[mi][ni];
#pragma unroll
        for (int r = 0; r < 4; ++r) {
          float h = v[r] + bv;
          float gl = 0.5f * h * (1.0f + erff(h * 0.70710678118654752f));
          Hout[(size_t)(row + r) * N + col] = f2bf(gl);
        }
      }
    }
  } else {
    const bool ab = (blockIdx.z == 0);
#pragma unroll
    for (int mi = 0; mi < 4; ++mi) {
      const int row = rowb + mi * 16;
      int tk[4]; float gk[4];
#pragma unroll
      for (int r = 0; r < 4; ++r) { tk[r] = slot_src[row + r]; gk[r] = slot_gate[row + r]; }
#pragma unroll
      for (int ni = 0; ni < 4; ++ni) {
        const int col = colb + ni * 16 + rm;
        const float bv = ab ? bias[col] : 0.0f;
        f32x4 v = acc[mi][ni];
#pragma unroll
        for (int r = 0; r < 4; ++r) {
          if (tk[r] >= 0)
            atomicAdd(Yout + (size_t)tk[r] * DMODEL + col, gk[r] * (v[r] + bv));
        }
      }
    }
  }
}

extern "C" void kernel_launch(void* const* d_in, const int* in_sizes, int n_in,
                              void* d_out, int out_size, void* d_ws, size_t ws_size,
                              hipStream_t stream) {
  (void)in_sizes; (void)n_in;
  const float* x     = (const float*)d_in[0];
  const float* wg    = (const float*)d_in[1];
  const float* fc1_w = (const float*)d_in[2];
  const float* fc1_b = (const float*)d_in[3];
  const float* fc2_w = (const float*)d_in[4];
  const float* fc2_b = (const float*)d_in[5];
  float* y = (float*)d_out;

  char* w = (char*)d_ws;
  unsigned short* disp = (unsigned short*)(w);                 // 64 MiB
  unsigned short* Hbuf = (unsigned short*)(w + 67108864);      // 32 MiB
  unsigned short* W1T  = (unsigned short*)(w + 100663296);     // 32 MiB
  unsigned short* W2T  = (unsigned short*)(w + 134217728);     // 32 MiB
  int*   slot_src  = (int*)(w + 167772160);                    // 64 KiB
  float* slot_gate = (float*)(w + 167837696);                  // 64 KiB
  int*   eidx      = (int*)(w + 167903232);                    // 64 KiB
  float* egate     = (float*)(w + 167968768);                  // 64 KiB
  if (ws_size < (size_t)168034304) return;                     // fail loud, not corrupt

  hipMemsetAsync(d_out, 0, (size_t)out_size * sizeof(float), stream);
  hipMemsetAsync(slot_src, 0xFF, (size_t)NEXP * CAPACITY * sizeof(int), stream);

  gate_kernel<<<S_TOK / 4, 256, 0, stream>>>(x, wg, eidx, egate);
  scan_kernel<<<1, 256, 0, stream>>>(eidx, egate, slot_src, slot_gate);
  dispatch_kernel<<<NEXP * CAPACITY, 256, 0, stream>>>(x, slot_src, disp);

  for (int e = 0; e < NEXP; ++e) {
    transpose_kernel<<<dim3(HIDDEN_ / 64, DMODEL / 64), 256, 0, stream>>>(
        fc1_w + (size_t)e * DMODEL * HIDDEN_, W1T, DMODEL, HIDDEN_);
    gemm_kernel<0><<<dim3(HIDDEN_ / 128, CAPACITY / 128, 1), 256, 0, stream>>>(
        disp + (size_t)e * CAPACITY * DMODEL, W1T, CAPACITY, HIDDEN_, DMODEL, DMODEL,
        fc1_b + (size_t)e * HIDDEN_, Hbuf, nullptr, nullptr, nullptr);
    transpose_kernel<<<dim3(DMODEL / 64, HIDDEN_ / 64), 256, 0, stream>>>(
        fc2_w + (size_t)e * HIDDEN_ * DMODEL, W2T, HIDDEN_, DMODEL);
    gemm_kernel<1><<<dim3(DMODEL / 128, CAPACITY / 128, 2), 256, 0, stream>>>(
        Hbuf, W2T, CAPACITY, DMODEL, HIDDEN_, HIDDEN_ / 2,
        fc2_b + (size_t)e * DMODEL, nullptr, y, slot_src + e * CAPACITY,
        slot_gate + e * CAPACITY);
  }
}